// Round 7
// baseline (1235.875 us; speedup 1.0000x reference)
//
#include <hip/hip_runtime.h>
#include <hip/hip_bf16.h>

#define N_NODES 40000
#define N_EDGES 640000
#define F_IN    1300
#define NH      4
#define NC      64
#define F_OUT   256   // NH*NC
#define NG      64
#define NEG_SLOPE 0.2f

typedef short short8v __attribute__((ext_vector_type(8)));
typedef float f32x16  __attribute__((ext_vector_type(16)));

__device__ __forceinline__ float lrelu(float x) { return x >= 0.f ? x : NEG_SLOPE * x; }

// bf16 round-to-nearest-even split helpers
__device__ __forceinline__ short f2bf(float v) {
    unsigned u = __builtin_bit_cast(unsigned, v);
    unsigned r = (u + 0x7fffu + ((u >> 16) & 1u)) >> 16;
    return (short)r;
}
__device__ __forceinline__ float bf2f(short s) {
    unsigned u = ((unsigned)(unsigned short)s) << 16;
    return __builtin_bit_cast(float, u);
}

__device__ __forceinline__ short8v ld8(const short* p) {
    short4 a = *(const short4*)(p);
    short4 b = *(const short4*)(p + 4);
    short8v r;
    r[0] = a.x; r[1] = a.y; r[2] = a.z; r[3] = a.w;
    r[4] = b.x; r[5] = b.y; r[6] = b.z; r[7] = b.w;
    return r;
}

// ---------------------------------------------------------------------------
// W pre-split: Wt_hi/Wt_lo[n][k] = bf16 split of W[k][n], k padded to Kp (zeros)
// ---------------------------------------------------------------------------
__global__ void wsplit_kernel(const float* __restrict__ W, short* __restrict__ hi,
                              short* __restrict__ lo, int K, int Kp)
{
    int idx = blockIdx.x * 256 + threadIdx.x;
    if (idx >= F_OUT * Kp) return;
    int n = idx / Kp, k = idx - n * Kp;
    float v = (k < K) ? W[(size_t)k * F_OUT + n] : 0.f;
    short h = f2bf(v);
    short l = f2bf(v - bf2f(h));
    hi[idx] = h;
    lo[idx] = l;
}

// ---------------------------------------------------------------------------
// GEMM v3: C[N,256] = A[N,K] @ B[K,256], bf16x3 MFMA.
// BM=32 -> grid 1250 (4-5 blocks/CU). A staged to LDS (dbuf, LDK=36);
// A-prefetch issued AFTER the barrier so its HBM latency hides under MFMA
// (barrier only drains the L2-hit B loads). B read straight to registers.
// 4 waves, each 32 rows x 64 cols (1x2 frags of 32x32x16).
// ---------------------------------------------------------------------------
#define BK  32
#define BMR 32
#define LDK 36   // row stride in shorts: 72B -> 2-way bank aliasing (free, m136)

__global__ __launch_bounds__(256, 4) void gemm_mfma_kernel(
    const float* __restrict__ A, const short* __restrict__ Bth,
    const short* __restrict__ Btl, float* __restrict__ C, int K, int Kp)
{
    __shared__ short As_hi[2][BMR][LDK];
    __shared__ short As_lo[2][BMR][LDK];

    const int t    = threadIdx.x;
    const int lane = t & 63;
    const int wv   = t >> 6;
    const int wc   = wv * 64;            // wave's column base (= head*64)
    const int bm   = blockIdx.x * BMR;

    f32x16 acc[2];
#pragma unroll
    for (int j = 0; j < 2; ++j)
#pragma unroll
        for (int r = 0; r < 16; ++r) acc[j][r] = 0.f;

    const int arow = t >> 3;             // 0..31
    const int ac   = (t & 7) * 4;        // 0..28
    const int mr   = lane & 31;
    const int khalf = (lane >> 5) * 8;   // 0 or 8

    const size_t abase = (size_t)(bm + arow) * K;
    const size_t b0 = (size_t)(wc + mr) * Kp + khalf;
    const size_t b1 = (size_t)(wc + 32 + mr) * Kp + khalf;

    const int nt = Kp / BK;

    // prologue: prefetch A tile 0
    float4 av = make_float4(0.f, 0.f, 0.f, 0.f);
    if (ac < K) av = *(const float4*)&A[abase + ac];

    for (int it = 0; it < nt; ++it) {
        const int k0  = it * BK;
        const int buf = it & 1;

        // B fragments for this iter (L2-resident)
        const short8v bh0_0 = *(const short8v*)&Bth[b0 + k0];
        const short8v bh0_1 = *(const short8v*)&Bth[b0 + k0 + 16];
        const short8v bh1_0 = *(const short8v*)&Bth[b1 + k0];
        const short8v bh1_1 = *(const short8v*)&Bth[b1 + k0 + 16];
        const short8v bl0_0 = *(const short8v*)&Btl[b0 + k0];
        const short8v bl0_1 = *(const short8v*)&Btl[b0 + k0 + 16];
        const short8v bl1_0 = *(const short8v*)&Btl[b1 + k0];
        const short8v bl1_1 = *(const short8v*)&Btl[b1 + k0 + 16];

        // convert + stage A tile `it`
        {
            short4 h4, l4;
            h4.x = f2bf(av.x); l4.x = f2bf(av.x - bf2f(h4.x));
            h4.y = f2bf(av.y); l4.y = f2bf(av.y - bf2f(h4.y));
            h4.z = f2bf(av.z); l4.z = f2bf(av.z - bf2f(h4.z));
            h4.w = f2bf(av.w); l4.w = f2bf(av.w - bf2f(h4.w));
            *(short4*)&As_hi[buf][arow][ac] = h4;
            *(short4*)&As_lo[buf][arow][ac] = l4;
        }

        __syncthreads();                       // drains B loads (L2) + LDS writes
        __builtin_amdgcn_sched_barrier(0);     // keep prefetch BELOW the barrier

        // prefetch A tile it+1 (HBM latency hides under the MFMA section)
        float4 nv = make_float4(0.f, 0.f, 0.f, 0.f);
        if (it + 1 < nt) {
            int gk = k0 + BK + ac;
            if (gk < K) nv = *(const float4*)&A[abase + gk];
        }

#pragma unroll
        for (int ks = 0; ks < 2; ++ks) {
            const int ko = ks * 16 + khalf;
            short8v ah = ld8(&As_hi[buf][mr][ko]);
            short8v al = ld8(&As_lo[buf][mr][ko]);
            const short8v bh0 = ks ? bh0_1 : bh0_0;
            const short8v bh1 = ks ? bh1_1 : bh1_0;
            const short8v bl0 = ks ? bl0_1 : bl0_0;
            const short8v bl1 = ks ? bl1_1 : bl1_0;
            acc[0] = __builtin_amdgcn_mfma_f32_32x32x16_bf16(ah, bh0, acc[0], 0, 0, 0);
            acc[0] = __builtin_amdgcn_mfma_f32_32x32x16_bf16(ah, bl0, acc[0], 0, 0, 0);
            acc[0] = __builtin_amdgcn_mfma_f32_32x32x16_bf16(al, bh0, acc[0], 0, 0, 0);
            acc[1] = __builtin_amdgcn_mfma_f32_32x32x16_bf16(ah, bh1, acc[1], 0, 0, 0);
            acc[1] = __builtin_amdgcn_mfma_f32_32x32x16_bf16(ah, bl1, acc[1], 0, 0, 0);
            acc[1] = __builtin_amdgcn_mfma_f32_32x32x16_bf16(al, bh1, acc[1], 0, 0, 0);
        }
        av = nv;
    }
    // epilogue: C/D layout (m74/m101): col=lane&31, row=(r&3)+8*(r>>2)+4*(lane>>5)
#pragma unroll
    for (int fn = 0; fn < 2; ++fn)
#pragma unroll
        for (int r = 0; r < 16; ++r) {
            int row = bm + (r & 3) + 8 * (r >> 2) + 4 * (lane >> 5);
            int col = wc + fn * 32 + mr;
            C[(size_t)row * F_OUT + col] = acc[fn][r];
        }
}

// ---------------------------------------------------------------------------
// attention coefficients: a_src[n][h] = sum_c h[n][h*64+c]*att_src[h][c]
// ---------------------------------------------------------------------------
__global__ __launch_bounds__(256) void attn_coef_kernel(const float* __restrict__ h,
                                                        const float* __restrict__ att_s,
                                                        const float* __restrict__ att_d,
                                                        float* __restrict__ a_s,
                                                        float* __restrict__ a_d)
{
    const int n = blockIdx.x;
    const int t = threadIdx.x;
    const int w = t >> 6;
    const int l = t & 63;
    float hv = h[(size_t)n * F_OUT + t];
    float vs = hv * att_s[t];
    float vd = hv * att_d[t];
#pragma unroll
    for (int o = 1; o < 64; o <<= 1) {
        vs += __shfl_xor(vs, o);
        vd += __shfl_xor(vd, o);
    }
    if (l == 0) {
        a_s[n * NH + w] = vs;
        a_d[n * NH + w] = vd;
    }
}

// ---------------------------------------------------------------------------
// CSR build (by destination)
// ---------------------------------------------------------------------------
__global__ void hist_kernel(const int* __restrict__ ei, int* __restrict__ deg)
{
    int e = blockIdx.x * blockDim.x + threadIdx.x;
    if (e < N_EDGES) atomicAdd(&deg[ei[N_EDGES + e]], 1);
}

__global__ __launch_bounds__(1024) void scan_kernel(const int* __restrict__ deg,
                                                    int* __restrict__ rowptr)
{
    __shared__ int sums[1024];
    const int t = threadIdx.x;
    const int chunk = (N_NODES + 1023) / 1024;
    int beg = t * chunk;
    int end = beg + chunk; if (end > N_NODES) end = N_NODES;
    if (beg > N_NODES) beg = N_NODES;
    int s = 0;
    for (int i = beg; i < end; ++i) s += deg[i];
    sums[t] = s;
    __syncthreads();
    for (int o = 1; o < 1024; o <<= 1) {
        int v = (t >= o) ? sums[t - o] : 0;
        __syncthreads();
        sums[t] += v;
        __syncthreads();
    }
    int run = (t == 0) ? 0 : sums[t - 1];
    for (int i = beg; i < end; ++i) { rowptr[i] = run; run += deg[i]; }
    if (t == 1023) rowptr[N_NODES] = run;
}

__global__ void scatter_kernel(const int* __restrict__ ei, int* __restrict__ cursor,
                               int* __restrict__ ssrc, int* __restrict__ edst)
{
    int e = blockIdx.x * blockDim.x + threadIdx.x;
    if (e < N_EDGES) {
        int d = ei[N_EDGES + e];
        int pos = atomicAdd(&cursor[d], 1);
        ssrc[pos] = ei[e];
        edst[pos] = d;
    }
}

// ---------------------------------------------------------------------------
// per-edge logits in CSR order (coalesced writes; scattered reads hit the
// 640KB L2-resident a_s/a_d): e_csr[p][h] = lrelu(a_s[src][h] + a_d[dst][h])
// ---------------------------------------------------------------------------
__global__ void edge_logit_kernel(const int* __restrict__ ssrc,
                                  const int* __restrict__ edst,
                                  const float* __restrict__ a_s,
                                  const float* __restrict__ a_d,
                                  float* __restrict__ e_csr)
{
    int p = blockIdx.x * 256 + threadIdx.x;
    if (p >= N_EDGES) return;
    int s = ssrc[p], d = edst[p];
    float4 as = ((const float4*)a_s)[s];
    float4 ad = ((const float4*)a_d)[d];
    float4 e;
    e.x = lrelu(as.x + ad.x);
    e.y = lrelu(as.y + ad.y);
    e.z = lrelu(as.z + ad.z);
    e.w = lrelu(as.w + ad.w);
    ((float4*)e_csr)[p] = e;
}

// ---------------------------------------------------------------------------
// GAT aggregation v3: wave per node.
// Phase A: per-head max & denom from SEQUENTIAL e_csr reads
//          (lane l <-> edge l>>2, head l&3; 256B coalesced lines).
// Phase B: weighted gather, lane l <-> channels 4l..4l+3 (head l>>4),
//          8-deep unrolled h-row loads for memory-level parallelism.
// ---------------------------------------------------------------------------
__global__ __launch_bounds__(256) void agg_kernel(const float* __restrict__ h,
                                                  const float* __restrict__ e_csr,
                                                  const float* __restrict__ a_s,
                                                  const float* __restrict__ a_d,
                                                  const int* __restrict__ rowptr,
                                                  const int* __restrict__ ssrc,
                                                  const float* __restrict__ bias,
                                                  float* __restrict__ out)
{
    const int wv = threadIdx.x >> 6;
    const int n  = blockIdx.x * 4 + wv;
    const int l  = threadIdx.x & 63;

    const int beg = rowptr[n];
    const int deg = rowptr[n + 1] - beg;

    // ---- phase A (head hA = l&3) ----
    const int hA = l & 3;
    const float es = lrelu(a_s[n * NH + hA] + a_d[n * NH + hA]);  // self logit
    const float* ep = e_csr + (size_t)beg * 4;

    float mx = es;
    for (int base = 0; base < deg; base += 16) {
        int i = base + (l >> 2);
        float e = (i < deg) ? ep[(size_t)i * 4 + hA] : -1e30f;
        mx = fmaxf(mx, e);
    }
#pragma unroll
    for (int o = 4; o < 64; o <<= 1) mx = fmaxf(mx, __shfl_xor(mx, o));

    float sm = ((l >> 2) == 0) ? __expf(es - mx) : 0.f;
    for (int base = 0; base < deg; base += 16) {
        int i = base + (l >> 2);
        sm += (i < deg) ? __expf(ep[(size_t)i * 4 + hA] - mx) : 0.f;
    }
#pragma unroll
    for (int o = 4; o < 64; o <<= 1) sm += __shfl_xor(sm, o);
    const float dinv = 1.f / (sm + 1e-16f);

    // ---- rekey to phase B (head hB = l>>4): lane hB holds head-hB values ----
    const int hB = l >> 4;
    const float mxB = __shfl(mx, hB);
    const float dvB = __shfl(dinv, hB);
    const float esB = __shfl(es, hB);

    // ---- phase B: gather ----
    const float4* h4 = (const float4*)h;
    float4 acc;
    {
        float sa = __expf(esB - mxB) * dvB;
        float4 hv = h4[(size_t)n * 64 + l];
        acc.x = sa * hv.x; acc.y = sa * hv.y; acc.z = sa * hv.z; acc.w = sa * hv.w;
    }
    int i = 0;
    for (; i + 8 <= deg; i += 8) {
        const int p = beg + i;
        int   s[8]; float e[8]; float4 v[8];
#pragma unroll
        for (int j = 0; j < 8; ++j) s[j] = ssrc[p + j];
#pragma unroll
        for (int j = 0; j < 8; ++j) e[j] = e_csr[(size_t)(p + j) * 4 + hB];
#pragma unroll
        for (int j = 0; j < 8; ++j) v[j] = h4[(size_t)s[j] * 64 + l];
#pragma unroll
        for (int j = 0; j < 8; ++j) {
            float a = __expf(e[j] - mxB) * dvB;
            acc.x += a * v[j].x; acc.y += a * v[j].y;
            acc.z += a * v[j].z; acc.w += a * v[j].w;
        }
    }
    for (; i < deg; ++i) {
        const int p = beg + i;
        int sj = ssrc[p];
        float a = __expf(e_csr[(size_t)p * 4 + hB] - mxB) * dvB;
        float4 hv = h4[(size_t)sj * 64 + l];
        acc.x += a * hv.x; acc.y += a * hv.y; acc.z += a * hv.z; acc.w += a * hv.w;
    }
    float4 bv = ((const float4*)bias)[l];
    float4 ov;
    ov.x = fmaxf(acc.x + bv.x, 0.f);
    ov.y = fmaxf(acc.y + bv.y, 0.f);
    ov.z = fmaxf(acc.z + bv.z, 0.f);
    ov.w = fmaxf(acc.w + bv.w, 0.f);
    ((float4*)out)[(size_t)n * 64 + l] = ov;
}

// ---------------------------------------------------------------------------
// graph histogram + fused mean-pool + linear head
// ---------------------------------------------------------------------------
__global__ void ghist_kernel(const int* __restrict__ batch, int* __restrict__ gcnt)
{
    int n = blockIdx.x * blockDim.x + threadIdx.x;
    if (n < N_NODES) atomicAdd(&gcnt[batch[n]], 1);
}

__global__ __launch_bounds__(256) void pool_kernel(const float* __restrict__ x,
                                                   const int* __restrict__ gcnt,
                                                   const float* __restrict__ lin_w,
                                                   const float* __restrict__ lin_b,
                                                   float* __restrict__ out)
{
    const int g = blockIdx.x;
    const int t = threadIdx.x;
    __shared__ int s_start;
    if (t == 0) {
        int s = 0;
        for (int i = 0; i < g; ++i) s += gcnt[i];
        s_start = s;
    }
    __syncthreads();
    const int start = s_start;
    const int cnt = gcnt[g];
    float acc = 0.f;
    for (int i = 0; i < cnt; ++i) acc += x[(size_t)(start + i) * F_OUT + t];
    float p = acc / fmaxf((float)cnt, 1.f);
    float v = p * lin_w[t];
    __shared__ float red[256];
    red[t] = v;
    __syncthreads();
    for (int o = 128; o > 0; o >>= 1) {
        if (t < o) red[t] += red[t + o];
        __syncthreads();
    }
    if (t == 0) out[g] = red[0] + lin_b[0];
}

// ---------------------------------------------------------------------------
extern "C" void kernel_launch(void* const* d_in, const int* in_sizes, int n_in,
                              void* d_out, int out_size, void* d_ws, size_t ws_size,
                              hipStream_t stream)
{
    const float* x      = (const float*)d_in[0];
    const int*   ei     = (const int*)  d_in[1];
    const int*   batch  = (const int*)  d_in[2];
    const float* W1     = (const float*)d_in[3];
    const float* att_s1 = (const float*)d_in[4];
    const float* att_d1 = (const float*)d_in[5];
    const float* b1     = (const float*)d_in[6];
    const float* W2     = (const float*)d_in[7];
    const float* att_s2 = (const float*)d_in[8];
    const float* att_d2 = (const float*)d_in[9];
    const float* b2     = (const float*)d_in[10];
    const float* lin_w  = (const float*)d_in[11];
    const float* lin_b  = (const float*)d_in[12];
    float* out = (float*)d_out;

    const int Kp1 = 1312;   // 1300 padded to x32
    const int Kp2 = 256;

    size_t off = 0;
    auto carve = [&](size_t bytes) -> void* {
        void* p = (char*)d_ws + off;
        off += (bytes + 255) & ~(size_t)255;
        return p;
    };
    float* hA     = (float*)carve((size_t)N_NODES * F_OUT * 4);
    float* hB     = (float*)carve((size_t)N_NODES * F_OUT * 4);
    float* a_s    = (float*)carve((size_t)N_NODES * NH * 4);
    float* a_d    = (float*)carve((size_t)N_NODES * NH * 4);
    int*   deg    = (int*)  carve((size_t)(N_NODES + 1) * 4);
    int*   rowptr = (int*)  carve((size_t)(N_NODES + 1) * 4);
    int*   cursor = (int*)  carve((size_t)N_NODES * 4);
    int*   ssrc   = (int*)  carve((size_t)N_EDGES * 4);
    int*   edst   = (int*)  carve((size_t)N_EDGES * 4);
    float* e_csr  = (float*)carve((size_t)N_EDGES * NH * 4);
    int*   gcnt   = (int*)  carve((size_t)NG * 4);
    short* Bt1h   = (short*)carve((size_t)F_OUT * Kp1 * 2);
    short* Bt1l   = (short*)carve((size_t)F_OUT * Kp1 * 2);
    short* Bt2h   = (short*)carve((size_t)F_OUT * Kp2 * 2);
    short* Bt2l   = (short*)carve((size_t)F_OUT * Kp2 * 2);
    (void)ws_size; (void)n_in; (void)in_sizes; (void)out_size;

    // ---- CSR build + weight pre-split ----
    hipMemsetAsync(deg, 0, (size_t)(N_NODES + 1) * 4, stream);
    hipMemsetAsync(gcnt, 0, (size_t)NG * 4, stream);
    hist_kernel<<<(N_EDGES + 255) / 256, 256, 0, stream>>>(ei, deg);
    scan_kernel<<<1, 1024, 0, stream>>>(deg, rowptr);
    hipMemcpyAsync(cursor, rowptr, (size_t)N_NODES * 4, hipMemcpyDeviceToDevice, stream);
    scatter_kernel<<<(N_EDGES + 255) / 256, 256, 0, stream>>>(ei, cursor, ssrc, edst);
    ghist_kernel<<<(N_NODES + 255) / 256, 256, 0, stream>>>(batch, gcnt);
    wsplit_kernel<<<(F_OUT * Kp1 + 255) / 256, 256, 0, stream>>>(W1, Bt1h, Bt1l, F_IN, Kp1);
    wsplit_kernel<<<(F_OUT * Kp2 + 255) / 256, 256, 0, stream>>>(W2, Bt2h, Bt2l, F_OUT, Kp2);

    const int gblocks = N_NODES / BMR;  // 1250
    const int ablocks = N_NODES / 4;    // 10000 (wave per node)
    const int eblocks = (N_EDGES + 255) / 256;

    // ---- layer 1 ----
    gemm_mfma_kernel<<<gblocks, 256, 0, stream>>>(x, Bt1h, Bt1l, hA, F_IN, Kp1);
    attn_coef_kernel<<<N_NODES, 256, 0, stream>>>(hA, att_s1, att_d1, a_s, a_d);
    edge_logit_kernel<<<eblocks, 256, 0, stream>>>(ssrc, edst, a_s, a_d, e_csr);
    agg_kernel<<<ablocks, 256, 0, stream>>>(hA, e_csr, a_s, a_d, rowptr, ssrc, b1, hB);

    // ---- layer 2 ----
    gemm_mfma_kernel<<<gblocks, 256, 0, stream>>>(hB, Bt2h, Bt2l, hA, F_OUT, Kp2);
    attn_coef_kernel<<<N_NODES, 256, 0, stream>>>(hA, att_s2, att_d2, a_s, a_d);
    edge_logit_kernel<<<eblocks, 256, 0, stream>>>(ssrc, edst, a_s, a_d, e_csr);
    agg_kernel<<<ablocks, 256, 0, stream>>>(hA, e_csr, a_s, a_d, rowptr, ssrc, b2, hB);

    // ---- pool + head ----
    pool_kernel<<<NG, 256, 0, stream>>>(hB, gcnt, lin_w, lin_b, out);
}

// Round 9
// 1208.354 us; speedup vs baseline: 1.0228x; 1.0228x over previous
//
#include <hip/hip_runtime.h>
#include <hip/hip_bf16.h>

#define N_NODES 40000
#define N_EDGES 640000
#define F_IN    1300
#define NH      4
#define NC      64
#define F_OUT   256   // NH*NC
#define NG      64
#define NEG_SLOPE 0.2f

typedef short short8v __attribute__((ext_vector_type(8)));
typedef float f32x16  __attribute__((ext_vector_type(16)));

__device__ __forceinline__ float lrelu(float x) { return x >= 0.f ? x : NEG_SLOPE * x; }

// bf16 round-to-nearest-even split helpers
__device__ __forceinline__ short f2bf(float v) {
    unsigned u = __builtin_bit_cast(unsigned, v);
    unsigned r = (u + 0x7fffu + ((u >> 16) & 1u)) >> 16;
    return (short)r;
}
__device__ __forceinline__ float bf2f(short s) {
    unsigned u = ((unsigned)(unsigned short)s) << 16;
    return __builtin_bit_cast(float, u);
}

// 8B LDS ops (rows are 72B-strided -> only 8B aligned)
__device__ __forceinline__ short8v ld8(const short* p) {
    short4 a = *(const short4*)(p);
    short4 b = *(const short4*)(p + 4);
    short8v r;
    r[0] = a.x; r[1] = a.y; r[2] = a.z; r[3] = a.w;
    r[4] = b.x; r[5] = b.y; r[6] = b.z; r[7] = b.w;
    return r;
}
__device__ __forceinline__ void st8(short* p, short8v v) {
    short4 a, b;
    a.x = v[0]; a.y = v[1]; a.z = v[2]; a.w = v[3];
    b.x = v[4]; b.y = v[5]; b.z = v[6]; b.w = v[7];
    *(short4*)(p)     = a;
    *(short4*)(p + 4) = b;
}

// split 8 f32 -> bf16 hi/lo fragments
__device__ __forceinline__ void cvt8(const float4 a, const float4 b,
                                     short8v &h, short8v &l)
{
    h[0] = f2bf(a.x); l[0] = f2bf(a.x - bf2f(h[0]));
    h[1] = f2bf(a.y); l[1] = f2bf(a.y - bf2f(h[1]));
    h[2] = f2bf(a.z); l[2] = f2bf(a.z - bf2f(h[2]));
    h[3] = f2bf(a.w); l[3] = f2bf(a.w - bf2f(h[3]));
    h[4] = f2bf(b.x); l[4] = f2bf(b.x - bf2f(h[4]));
    h[5] = f2bf(b.y); l[5] = f2bf(b.y - bf2f(h[5]));
    h[6] = f2bf(b.z); l[6] = f2bf(b.z - bf2f(h[6]));
    h[7] = f2bf(b.w); l[7] = f2bf(b.w - bf2f(h[7]));
}

// ---------------------------------------------------------------------------
// W pre-split: Wt_hi/Wt_lo[n][k] = bf16 split of W[k][n], k padded to Kp (zeros)
// ---------------------------------------------------------------------------
__global__ void wsplit_kernel(const float* __restrict__ W, short* __restrict__ hi,
                              short* __restrict__ lo, int K, int Kp)
{
    int idx = blockIdx.x * 256 + threadIdx.x;
    if (idx >= F_OUT * Kp) return;
    int n = idx / Kp, k = idx - n * Kp;
    float v = (k < K) ? W[(size_t)k * F_OUT + n] : 0.f;
    short h = f2bf(v);
    short l = f2bf(v - bf2f(h));
    hi[idx] = h;
    lo[idx] = l;
}

// ---------------------------------------------------------------------------
// GEMM v4: C[N,256] = A[N,K] @ B[K,256], bf16x3 MFMA.
// A: NEVER staged -- per-lane register loads straight from global (HBM),
//    issued one 32k-tile ahead; no barrier ever drains them (counted vmcnt).
// B: LDS double-buffer (72KB), staged from L2; raw s_barrier + lgkmcnt(0)
//    only -- the ds_write's data-dep waitcnt counts only the B loads
//    (issued BEFORE the A loads, so vmcnt leaves A in flight).
// Block: 64 rows x 256 cols (4 waves; wave = 32 rows x 128 cols, 4 frags).
// Grid: 625 (exact). A read exactly once = 208 MB.
// ---------------------------------------------------------------------------
#define LDB 36   // B row stride in shorts: 72B -> 2-way bank aliasing (free)

__global__ __launch_bounds__(256, 2) void gemm_mfma_kernel(
    const float* __restrict__ A, const short* __restrict__ Bth,
    const short* __restrict__ Btl, float* __restrict__ C, int K, int Kp)
{
    __shared__ short Bs_hi[2][256][LDB];
    __shared__ short Bs_lo[2][256][LDB];

    const int t     = threadIdx.x;
    const int lane  = t & 63;
    const int wv    = t >> 6;
    const int mr    = lane & 31;
    const int khalf = (lane >> 5) * 8;          // 0 or 8
    const int rbase = blockIdx.x * 64 + (wv >> 1) * 32;
    const int cbase = (wv & 1) * 128;

    f32x16 acc[4];
#pragma unroll
    for (int j = 0; j < 4; ++j)
#pragma unroll
        for (int r = 0; r < 16; ++r) acc[j][r] = 0.f;

    const int nt = Kp / 32;
    const size_t arow = (size_t)(rbase + mr) * K;
    const size_t bcol = (size_t)t * Kp;

    // guarded 8-f32 A load at A[row][kg..kg+8)
    auto loadA8 = [&](int kg, float4 &x, float4 &y) {
        if (kg + 8 <= K) {
            x = *(const float4*)&A[arow + kg];
            y = *(const float4*)&A[arow + kg + 4];
        } else {
            float v0 = (kg + 0 < K) ? A[arow + kg + 0] : 0.f;
            float v1 = (kg + 1 < K) ? A[arow + kg + 1] : 0.f;
            float v2 = (kg + 2 < K) ? A[arow + kg + 2] : 0.f;
            float v3 = (kg + 3 < K) ? A[arow + kg + 3] : 0.f;
            float v4 = (kg + 4 < K) ? A[arow + kg + 4] : 0.f;
            float v5 = (kg + 5 < K) ? A[arow + kg + 5] : 0.f;
            float v6 = (kg + 6 < K) ? A[arow + kg + 6] : 0.f;
            float v7 = (kg + 7 < K) ? A[arow + kg + 7] : 0.f;
            x = make_float4(v0, v1, v2, v3);
            y = make_float4(v4, v5, v6, v7);
        }
    };

    // ---- prologue: tile 0 ----
    short8v pbh0, pbh1, pbh2, pbh3, pbl0, pbl1, pbl2, pbl3;
    pbh0 = *(const short8v*)&Bth[bcol + 0];
    pbh1 = *(const short8v*)&Bth[bcol + 8];
    pbh2 = *(const short8v*)&Bth[bcol + 16];
    pbh3 = *(const short8v*)&Bth[bcol + 24];
    pbl0 = *(const short8v*)&Btl[bcol + 0];
    pbl1 = *(const short8v*)&Btl[bcol + 8];
    pbl2 = *(const short8v*)&Btl[bcol + 16];
    pbl3 = *(const short8v*)&Btl[bcol + 24];
    float4 a0x, a0y, a1x, a1y;
    loadA8(khalf, a0x, a0y);
    loadA8(16 + khalf, a1x, a1y);
    st8(&Bs_hi[0][t][0],  pbh0);
    st8(&Bs_hi[0][t][8],  pbh1);
    st8(&Bs_hi[0][t][16], pbh2);
    st8(&Bs_hi[0][t][24], pbh3);
    st8(&Bs_lo[0][t][0],  pbl0);
    st8(&Bs_lo[0][t][8],  pbl1);
    st8(&Bs_lo[0][t][16], pbl2);
    st8(&Bs_lo[0][t][24], pbl3);
    asm volatile("s_waitcnt lgkmcnt(0)" ::: "memory");
    __builtin_amdgcn_sched_barrier(0);
    __builtin_amdgcn_s_barrier();

    for (int it = 0; it < nt; ++it) {
        const int buf  = it & 1;
        const bool more = (it + 1 < nt);
        const int k0n  = (it + 1) * 32;

        // issue next-tile loads: B FIRST (L2), then A (HBM stays in flight)
        short8v nbh0, nbh1, nbh2, nbh3, nbl0, nbl1, nbl2, nbl3;
        float4 na0x, na0y, na1x, na1y;
        if (more) {
            nbh0 = *(const short8v*)&Bth[bcol + k0n + 0];
            nbh1 = *(const short8v*)&Bth[bcol + k0n + 8];
            nbh2 = *(const short8v*)&Bth[bcol + k0n + 16];
            nbh3 = *(const short8v*)&Bth[bcol + k0n + 24];
            nbl0 = *(const short8v*)&Btl[bcol + k0n + 0];
            nbl1 = *(const short8v*)&Btl[bcol + k0n + 8];
            nbl2 = *(const short8v*)&Btl[bcol + k0n + 16];
            nbl3 = *(const short8v*)&Btl[bcol + k0n + 24];
            loadA8(k0n + khalf, na0x, na0y);
            loadA8(k0n + 16 + khalf, na1x, na1y);
        } else {
            nbh0 = nbh1 = nbh2 = nbh3 = (short8v)0;
            nbl0 = nbl1 = nbl2 = nbl3 = (short8v)0;
            na0x = na0y = na1x = na1y = make_float4(0.f, 0.f, 0.f, 0.f);
        }

        // ---- compute tile it: 2 k16-steps x 4 col-frags x 3 mfma ----
        {
            short8v ah, al;
            cvt8(a0x, a0y, ah, al);
#pragma unroll
            for (int cf = 0; cf < 4; ++cf) {
                const short* ph = &Bs_hi[buf][cbase + cf * 32 + mr][khalf];
                const short* pl = &Bs_lo[buf][cbase + cf * 32 + mr][khalf];
                short8v bh = ld8(ph);
                short8v bl = ld8(pl);
                acc[cf] = __builtin_amdgcn_mfma_f32_32x32x16_bf16(ah, bh, acc[cf], 0, 0, 0);
                acc[cf] = __builtin_amdgcn_mfma_f32_32x32x16_bf16(ah, bl, acc[cf], 0, 0, 0);
                acc[cf] = __builtin_amdgcn_mfma_f32_32x32x16_bf16(al, bh, acc[cf], 0, 0, 0);
            }
            cvt8(a1x, a1y, ah, al);
#pragma unroll
            for (int cf = 0; cf < 4; ++cf) {
                const short* ph = &Bs_hi[buf][cbase + cf * 32 + mr][16 + khalf];
                const short* pl = &Bs_lo[buf][cbase + cf * 32 + mr][16 + khalf];
                short8v bh = ld8(ph);
                short8v bl = ld8(pl);
                acc[cf] = __builtin_amdgcn_mfma_f32_32x32x16_bf16(ah, bh, acc[cf], 0, 0, 0);
                acc[cf] = __builtin_amdgcn_mfma_f32_32x32x16_bf16(ah, bl, acc[cf], 0, 0, 0);
                acc[cf] = __builtin_amdgcn_mfma_f32_32x32x16_bf16(al, bh, acc[cf], 0, 0, 0);
            }
        }

        // stage next B tile (waitcnt here counts only B loads; A stays in flight)
        if (more) {
            st8(&Bs_hi[buf ^ 1][t][0],  nbh0);
            st8(&Bs_hi[buf ^ 1][t][8],  nbh1);
            st8(&Bs_hi[buf ^ 1][t][16], nbh2);
            st8(&Bs_hi[buf ^ 1][t][24], nbh3);
            st8(&Bs_lo[buf ^ 1][t][0],  nbl0);
            st8(&Bs_lo[buf ^ 1][t][8],  nbl1);
            st8(&Bs_lo[buf ^ 1][t][16], nbl2);
            st8(&Bs_lo[buf ^ 1][t][24], nbl3);
        }
        asm volatile("s_waitcnt lgkmcnt(0)" ::: "memory");
        __builtin_amdgcn_sched_barrier(0);
        __builtin_amdgcn_s_barrier();

        a0x = na0x; a0y = na0y; a1x = na1x; a1y = na1y;
    }

    // epilogue: C/D layout (m74/m101): col=lane&31, row=(r&3)+8*(r>>2)+4*(lane>>5)
#pragma unroll
    for (int cf = 0; cf < 4; ++cf)
#pragma unroll
        for (int r = 0; r < 16; ++r) {
            int row = rbase + (r & 3) + 8 * (r >> 2) + 4 * (lane >> 5);
            int col = cbase + cf * 32 + mr;
            C[(size_t)row * F_OUT + col] = acc[cf][r];
        }
}

// ---------------------------------------------------------------------------
// attention coefficients: a_src[n][h] = sum_c h[n][h*64+c]*att_src[h][c]
// ---------------------------------------------------------------------------
__global__ __launch_bounds__(256) void attn_coef_kernel(const float* __restrict__ h,
                                                        const float* __restrict__ att_s,
                                                        const float* __restrict__ att_d,
                                                        float* __restrict__ a_s,
                                                        float* __restrict__ a_d)
{
    const int n = blockIdx.x;
    const int t = threadIdx.x;
    const int w = t >> 6;
    const int l = t & 63;
    float hv = h[(size_t)n * F_OUT + t];
    float vs = hv * att_s[t];
    float vd = hv * att_d[t];
#pragma unroll
    for (int o = 1; o < 64; o <<= 1) {
        vs += __shfl_xor(vs, o);
        vd += __shfl_xor(vd, o);
    }
    if (l == 0) {
        a_s[n * NH + w] = vs;
        a_d[n * NH + w] = vd;
    }
}

// ---------------------------------------------------------------------------
// CSR build (by destination)
// ---------------------------------------------------------------------------
__global__ void hist_kernel(const int* __restrict__ ei, int* __restrict__ deg)
{
    int e = blockIdx.x * blockDim.x + threadIdx.x;
    if (e < N_EDGES) atomicAdd(&deg[ei[N_EDGES + e]], 1);
}

__global__ __launch_bounds__(1024) void scan_kernel(const int* __restrict__ deg,
                                                    int* __restrict__ rowptr)
{
    __shared__ int sums[1024];
    const int t = threadIdx.x;
    const int chunk = (N_NODES + 1023) / 1024;
    int beg = t * chunk;
    int end = beg + chunk; if (end > N_NODES) end = N_NODES;
    if (beg > N_NODES) beg = N_NODES;
    int s = 0;
    for (int i = beg; i < end; ++i) s += deg[i];
    sums[t] = s;
    __syncthreads();
    for (int o = 1; o < 1024; o <<= 1) {
        int v = (t >= o) ? sums[t - o] : 0;
        __syncthreads();
        sums[t] += v;
        __syncthreads();
    }
    int run = (t == 0) ? 0 : sums[t - 1];
    for (int i = beg; i < end; ++i) { rowptr[i] = run; run += deg[i]; }
    if (t == 1023) rowptr[N_NODES] = run;
}

__global__ void scatter_kernel(const int* __restrict__ ei, int* __restrict__ cursor,
                               int* __restrict__ ssrc, int* __restrict__ edst)
{
    int e = blockIdx.x * blockDim.x + threadIdx.x;
    if (e < N_EDGES) {
        int d = ei[N_EDGES + e];
        int pos = atomicAdd(&cursor[d], 1);
        ssrc[pos] = ei[e];
        edst[pos] = d;
    }
}

// ---------------------------------------------------------------------------
// per-edge logits in CSR order
// ---------------------------------------------------------------------------
__global__ void edge_logit_kernel(const int* __restrict__ ssrc,
                                  const int* __restrict__ edst,
                                  const float* __restrict__ a_s,
                                  const float* __restrict__ a_d,
                                  float* __restrict__ e_csr)
{
    int p = blockIdx.x * 256 + threadIdx.x;
    if (p >= N_EDGES) return;
    int s = ssrc[p], d = edst[p];
    float4 as = ((const float4*)a_s)[s];
    float4 ad = ((const float4*)a_d)[d];
    float4 e;
    e.x = lrelu(as.x + ad.x);
    e.y = lrelu(as.y + ad.y);
    e.z = lrelu(as.z + ad.z);
    e.w = lrelu(as.w + ad.w);
    ((float4*)e_csr)[p] = e;
}

// ---------------------------------------------------------------------------
// GAT aggregation v3: wave per node (unchanged from round 7)
// ---------------------------------------------------------------------------
__global__ __launch_bounds__(256) void agg_kernel(const float* __restrict__ h,
                                                  const float* __restrict__ e_csr,
                                                  const float* __restrict__ a_s,
                                                  const float* __restrict__ a_d,
                                                  const int* __restrict__ rowptr,
                                                  const int* __restrict__ ssrc,
                                                  const float* __restrict__ bias,
                                                  float* __restrict__ out)
{
    const int wv = threadIdx.x >> 6;
    const int n  = blockIdx.x * 4 + wv;
    const int l  = threadIdx.x & 63;

    const int beg = rowptr[n];
    const int deg = rowptr[n + 1] - beg;

    // ---- phase A (head hA = l&3) ----
    const int hA = l & 3;
    const float es = lrelu(a_s[n * NH + hA] + a_d[n * NH + hA]);
    const float* ep = e_csr + (size_t)beg * 4;

    float mx = es;
    for (int base = 0; base < deg; base += 16) {
        int i = base + (l >> 2);
        float e = (i < deg) ? ep[(size_t)i * 4 + hA] : -1e30f;
        mx = fmaxf(mx, e);
    }
#pragma unroll
    for (int o = 4; o < 64; o <<= 1) mx = fmaxf(mx, __shfl_xor(mx, o));

    float sm = ((l >> 2) == 0) ? __expf(es - mx) : 0.f;
    for (int base = 0; base < deg; base += 16) {
        int i = base + (l >> 2);
        sm += (i < deg) ? __expf(ep[(size_t)i * 4 + hA] - mx) : 0.f;
    }
#pragma unroll
    for (int o = 4; o < 64; o <<= 1) sm += __shfl_xor(sm, o);
    const float dinv = 1.f / (sm + 1e-16f);

    // ---- rekey to phase B (head hB = l>>4) ----
    const int hB = l >> 4;
    const float mxB = __shfl(mx, hB);
    const float dvB = __shfl(dinv, hB);
    const float esB = __shfl(es, hB);

    // ---- phase B: gather ----
    const float4* h4 = (const float4*)h;
    float4 acc;
    {
        float sa = __expf(esB - mxB) * dvB;
        float4 hv = h4[(size_t)n * 64 + l];
        acc.x = sa * hv.x; acc.y = sa * hv.y; acc.z = sa * hv.z; acc.w = sa * hv.w;
    }
    int i = 0;
    for (; i + 8 <= deg; i += 8) {
        const int p = beg + i;
        int   s[8]; float e[8]; float4 v[8];
#pragma unroll
        for (int j = 0; j < 8; ++j) s[j] = ssrc[p + j];
#pragma unroll
        for (int j = 0; j < 8; ++j) e[j] = e_csr[(size_t)(p + j) * 4 + hB];
#pragma unroll
        for (int j = 0; j < 8; ++j) v[j] = h4[(size_t)s[j] * 64 + l];
#pragma unroll
        for (int j = 0; j < 8; ++j) {
            float a = __expf(e[j] - mxB) * dvB;
            acc.x += a * v[j].x; acc.y += a * v[j].y;
            acc.z += a * v[j].z; acc.w += a * v[j].w;
        }
    }
    for (; i < deg; ++i) {
        const int p = beg + i;
        int sj = ssrc[p];
        float a = __expf(e_csr[(size_t)p * 4 + hB] - mxB) * dvB;
        float4 hv = h4[(size_t)sj * 64 + l];
        acc.x += a * hv.x; acc.y += a * hv.y; acc.z += a * hv.z; acc.w += a * hv.w;
    }
    float4 bv = ((const float4*)bias)[l];
    float4 ov;
    ov.x = fmaxf(acc.x + bv.x, 0.f);
    ov.y = fmaxf(acc.y + bv.y, 0.f);
    ov.z = fmaxf(acc.z + bv.z, 0.f);
    ov.w = fmaxf(acc.w + bv.w, 0.f);
    ((float4*)out)[(size_t)n * 64 + l] = ov;
}

// ---------------------------------------------------------------------------
// graph histogram + fused mean-pool + linear head
// ---------------------------------------------------------------------------
__global__ void ghist_kernel(const int* __restrict__ batch, int* __restrict__ gcnt)
{
    int n = blockIdx.x * blockDim.x + threadIdx.x;
    if (n < N_NODES) atomicAdd(&gcnt[batch[n]], 1);
}

__global__ __launch_bounds__(256) void pool_kernel(const float* __restrict__ x,
                                                   const int* __restrict__ gcnt,
                                                   const float* __restrict__ lin_w,
                                                   const float* __restrict__ lin_b,
                                                   float* __restrict__ out)
{
    const int g = blockIdx.x;
    const int t = threadIdx.x;
    __shared__ int s_start;
    if (t == 0) {
        int s = 0;
        for (int i = 0; i < g; ++i) s += gcnt[i];
        s_start = s;
    }
    __syncthreads();
    const int start = s_start;
    const int cnt = gcnt[g];
    float acc = 0.f;
    for (int i = 0; i < cnt; ++i) acc += x[(size_t)(start + i) * F_OUT + t];
    float p = acc / fmaxf((float)cnt, 1.f);
    float v = p * lin_w[t];
    __shared__ float red[256];
    red[t] = v;
    __syncthreads();
    for (int o = 128; o > 0; o >>= 1) {
        if (t < o) red[t] += red[t + o];
        __syncthreads();
    }
    if (t == 0) out[g] = red[0] + lin_b[0];
}

// ---------------------------------------------------------------------------
extern "C" void kernel_launch(void* const* d_in, const int* in_sizes, int n_in,
                              void* d_out, int out_size, void* d_ws, size_t ws_size,
                              hipStream_t stream)
{
    const float* x      = (const float*)d_in[0];
    const int*   ei     = (const int*)  d_in[1];
    const int*   batch  = (const int*)  d_in[2];
    const float* W1     = (const float*)d_in[3];
    const float* att_s1 = (const float*)d_in[4];
    const float* att_d1 = (const float*)d_in[5];
    const float* b1     = (const float*)d_in[6];
    const float* W2     = (const float*)d_in[7];
    const float* att_s2 = (const float*)d_in[8];
    const float* att_d2 = (const float*)d_in[9];
    const float* b2     = (const float*)d_in[10];
    const float* lin_w  = (const float*)d_in[11];
    const float* lin_b  = (const float*)d_in[12];
    float* out = (float*)d_out;

    const int Kp1 = 1312;   // 1300 padded to x32
    const int Kp2 = 256;

    size_t off = 0;
    auto carve = [&](size_t bytes) -> void* {
        void* p = (char*)d_ws + off;
        off += (bytes + 255) & ~(size_t)255;
        return p;
    };
    float* hA     = (float*)carve((size_t)N_NODES * F_OUT * 4);
    float* hB     = (float*)carve((size_t)N_NODES * F_OUT * 4);
    float* a_s    = (float*)carve((size_t)N_NODES * NH * 4);
    float* a_d    = (float*)carve((size_t)N_NODES * NH * 4);
    int*   deg    = (int*)  carve((size_t)(N_NODES + 1) * 4);
    int*   rowptr = (int*)  carve((size_t)(N_NODES + 1) * 4);
    int*   cursor = (int*)  carve((size_t)N_NODES * 4);
    int*   ssrc   = (int*)  carve((size_t)N_EDGES * 4);
    int*   edst   = (int*)  carve((size_t)N_EDGES * 4);
    float* e_csr  = (float*)carve((size_t)N_EDGES * NH * 4);
    int*   gcnt   = (int*)  carve((size_t)NG * 4);
    short* Bt1h   = (short*)carve((size_t)F_OUT * Kp1 * 2);
    short* Bt1l   = (short*)carve((size_t)F_OUT * Kp1 * 2);
    short* Bt2h   = (short*)carve((size_t)F_OUT * Kp2 * 2);
    short* Bt2l   = (short*)carve((size_t)F_OUT * Kp2 * 2);
    (void)ws_size; (void)n_in; (void)in_sizes; (void)out_size;

    // ---- CSR build + weight pre-split ----
    hipMemsetAsync(deg, 0, (size_t)(N_NODES + 1) * 4, stream);
    hipMemsetAsync(gcnt, 0, (size_t)NG * 4, stream);
    hist_kernel<<<(N_EDGES + 255) / 256, 256, 0, stream>>>(ei, deg);
    scan_kernel<<<1, 1024, 0, stream>>>(deg, rowptr);
    hipMemcpyAsync(cursor, rowptr, (size_t)N_NODES * 4, hipMemcpyDeviceToDevice, stream);
    scatter_kernel<<<(N_EDGES + 255) / 256, 256, 0, stream>>>(ei, cursor, ssrc, edst);
    ghist_kernel<<<(N_NODES + 255) / 256, 256, 0, stream>>>(batch, gcnt);
    wsplit_kernel<<<(F_OUT * Kp1 + 255) / 256, 256, 0, stream>>>(W1, Bt1h, Bt1l, F_IN, Kp1);
    wsplit_kernel<<<(F_OUT * Kp2 + 255) / 256, 256, 0, stream>>>(W2, Bt2h, Bt2l, F_OUT, Kp2);

    const int gblocks = N_NODES / 64;   // 625 (exact)
    const int ablocks = N_NODES / 4;    // 10000 (wave per node)
    const int eblocks = (N_EDGES + 255) / 256;

    // ---- layer 1 ----
    gemm_mfma_kernel<<<gblocks, 256, 0, stream>>>(x, Bt1h, Bt1l, hA, F_IN, Kp1);
    attn_coef_kernel<<<N_NODES, 256, 0, stream>>>(hA, att_s1, att_d1, a_s, a_d);
    edge_logit_kernel<<<eblocks, 256, 0, stream>>>(ssrc, edst, a_s, a_d, e_csr);
    agg_kernel<<<ablocks, 256, 0, stream>>>(hA, e_csr, a_s, a_d, rowptr, ssrc, b1, hB);

    // ---- layer 2 ----
    gemm_mfma_kernel<<<gblocks, 256, 0, stream>>>(hB, Bt2h, Bt2l, hA, F_OUT, Kp2);
    attn_coef_kernel<<<N_NODES, 256, 0, stream>>>(hA, att_s2, att_d2, a_s, a_d);
    edge_logit_kernel<<<eblocks, 256, 0, stream>>>(ssrc, edst, a_s, a_d, e_csr);
    agg_kernel<<<ablocks, 256, 0, stream>>>(hA, e_csr, a_s, a_d, rowptr, ssrc, b2, hB);

    // ---- pool + head ----
    pool_kernel<<<NG, 256, 0, stream>>>(hB, gcnt, lin_w, lin_b, out);
}

// Round 10
// 1070.995 us; speedup vs baseline: 1.1540x; 1.1283x over previous
//
#include <hip/hip_runtime.h>
#include <hip/hip_bf16.h>

#define N_NODES 40000
#define N_EDGES 640000
#define F_IN    1300
#define NH      4
#define NC      64
#define F_OUT   256   // NH*NC
#define NG      64
#define NEG_SLOPE 0.2f

typedef short short8v __attribute__((ext_vector_type(8)));
typedef float f32x16  __attribute__((ext_vector_type(16)));

__device__ __forceinline__ float lrelu(float x) { return x >= 0.f ? x : NEG_SLOPE * x; }

// bf16 round-to-nearest-even split helpers
__device__ __forceinline__ short f2bf(float v) {
    unsigned u = __builtin_bit_cast(unsigned, v);
    unsigned r = (u + 0x7fffu + ((u >> 16) & 1u)) >> 16;
    return (short)r;
}
__device__ __forceinline__ float bf2f(short s) {
    unsigned u = ((unsigned)(unsigned short)s) << 16;
    return __builtin_bit_cast(float, u);
}

// split 8 f32 -> bf16 hi/lo fragments
__device__ __forceinline__ void cvt8(const float4 a, const float4 b,
                                     short8v &h, short8v &l)
{
    h[0] = f2bf(a.x); l[0] = f2bf(a.x - bf2f(h[0]));
    h[1] = f2bf(a.y); l[1] = f2bf(a.y - bf2f(h[1]));
    h[2] = f2bf(a.z); l[2] = f2bf(a.z - bf2f(h[2]));
    h[3] = f2bf(a.w); l[3] = f2bf(a.w - bf2f(h[3]));
    h[4] = f2bf(b.x); l[4] = f2bf(b.x - bf2f(h[4]));
    h[5] = f2bf(b.y); l[5] = f2bf(b.y - bf2f(h[5]));
    h[6] = f2bf(b.z); l[6] = f2bf(b.z - bf2f(h[6]));
    h[7] = f2bf(b.w); l[7] = f2bf(b.w - bf2f(h[7]));
}

// ---------------------------------------------------------------------------
// W pre-split + TILE-PACK: for W[k][n] (n=output col), emit bf16 hi/lo at
// packed index ((k>>3)*256 + n)*8 + (k&7).  A fragment-load of 32 consecutive
// cols x 8 k-values is then 512 contiguous bytes -> fully coalesced.
// ---------------------------------------------------------------------------
__global__ void wsplit_kernel(const float* __restrict__ W, short* __restrict__ hi,
                              short* __restrict__ lo, int K, int Kp)
{
    int idx = blockIdx.x * 256 + threadIdx.x;   // idx = n*Kp + k
    if (idx >= F_OUT * Kp) return;
    int n = idx / Kp, k = idx - n * Kp;
    float v = (k < K) ? W[(size_t)k * F_OUT + n] : 0.f;
    short h = f2bf(v);
    short l = f2bf(v - bf2f(h));
    size_t po = ((size_t)(k >> 3) * F_OUT + n) * 8 + (k & 7);
    hi[po] = h;
    lo[po] = l;
}

// ---------------------------------------------------------------------------
// GEMM v5: C[N,256] = A[N,K] @ B[K,256], bf16x3 MFMA.
// NO LDS. NO BARRIERS. Every wave fully independent, self-paced.
// A: per-lane register loads (row=rbase+mr, k=khalf..), 1 tile ahead.
// B: per-lane register loads from tile-packed layout (coalesced 16B), 1 ahead.
// Block: 32 rows x 256 cols = 4 waves; wave = 32 rows x 64 cols (2 frags).
// Grid 1250. 12 MFMA / tile / wave.
// ---------------------------------------------------------------------------
#define BMR 32

__global__ __launch_bounds__(256, 3) void gemm_mfma_kernel(
    const float* __restrict__ A, const short* __restrict__ Bph,
    const short* __restrict__ Bpl, float* __restrict__ C, int K, int Kp)
{
    const int t     = threadIdx.x;
    const int lane  = t & 63;
    const int wv    = t >> 6;
    const int mr    = lane & 31;
    const int hs    = lane >> 5;         // k-half select (0/1)
    const int khalf = hs * 8;
    const int rbase = blockIdx.x * BMR;
    const int cbase = wv * 64;

    f32x16 acc[2];
#pragma unroll
    for (int j = 0; j < 2; ++j)
#pragma unroll
        for (int r = 0; r < 16; ++r) acc[j][r] = 0.f;

    const int nt = Kp / 32;
    const size_t arow = (size_t)(rbase + mr) * K;
    // packed-B lane base for col frag cf at k-chunk kk (kk multiple of 8):
    //   &Bp[((kk>>3)*256 + cbase + cf*32 + mr)*8]
    const int col0 = cbase + mr;
    const int col1 = cbase + 32 + mr;

    auto bptr = [&](const short* Bp, int kk, int col) -> const short8v* {
        return (const short8v*)&Bp[((size_t)(kk >> 3) * F_OUT + col) * 8];
    };

    // guarded 8-f32 A load at A[row][kg..kg+8)
    auto loadA8 = [&](int kg, float4 &x, float4 &y) {
        if (kg + 8 <= K) {
            x = *(const float4*)&A[arow + kg];
            y = *(const float4*)&A[arow + kg + 4];
        } else {
            float v0 = (kg + 0 < K) ? A[arow + kg + 0] : 0.f;
            float v1 = (kg + 1 < K) ? A[arow + kg + 1] : 0.f;
            float v2 = (kg + 2 < K) ? A[arow + kg + 2] : 0.f;
            float v3 = (kg + 3 < K) ? A[arow + kg + 3] : 0.f;
            float v4 = (kg + 4 < K) ? A[arow + kg + 4] : 0.f;
            float v5 = (kg + 5 < K) ? A[arow + kg + 5] : 0.f;
            float v6 = (kg + 6 < K) ? A[arow + kg + 6] : 0.f;
            float v7 = (kg + 7 < K) ? A[arow + kg + 7] : 0.f;
            x = make_float4(v0, v1, v2, v3);
            y = make_float4(v4, v5, v6, v7);
        }
    };

    // ---- prologue: tile 0 loads ----
    float4 a0x, a0y, a1x, a1y;                       // A: ks=0, ks=1
    short8v bh00, bh10, bh01, bh11, bl00, bl10, bl01, bl11; // b{h,l}{cf}{ks}
    loadA8(khalf, a0x, a0y);
    loadA8(16 + khalf, a1x, a1y);
    bh00 = *bptr(Bph, khalf,      col0);
    bh10 = *bptr(Bph, khalf,      col1);
    bh01 = *bptr(Bph, 16 + khalf, col0);
    bh11 = *bptr(Bph, 16 + khalf, col1);
    bl00 = *bptr(Bpl, khalf,      col0);
    bl10 = *bptr(Bpl, khalf,      col1);
    bl01 = *bptr(Bpl, 16 + khalf, col0);
    bl11 = *bptr(Bpl, 16 + khalf, col1);

    for (int it = 0; it < nt; ++it) {
        const bool more = (it + 1 < nt);
        const int k0n = (it + 1) * 32;

        // ---- prefetch tile it+1 ----
        float4 na0x, na0y, na1x, na1y;
        short8v nh00, nh10, nh01, nh11, nl00, nl10, nl01, nl11;
        if (more) {
            loadA8(k0n + khalf, na0x, na0y);
            loadA8(k0n + 16 + khalf, na1x, na1y);
            nh00 = *bptr(Bph, k0n + khalf,      col0);
            nh10 = *bptr(Bph, k0n + khalf,      col1);
            nh01 = *bptr(Bph, k0n + 16 + khalf, col0);
            nh11 = *bptr(Bph, k0n + 16 + khalf, col1);
            nl00 = *bptr(Bpl, k0n + khalf,      col0);
            nl10 = *bptr(Bpl, k0n + khalf,      col1);
            nl01 = *bptr(Bpl, k0n + 16 + khalf, col0);
            nl11 = *bptr(Bpl, k0n + 16 + khalf, col1);
        } else {
            na0x = na0y = na1x = na1y = make_float4(0.f, 0.f, 0.f, 0.f);
            nh00 = nh10 = nh01 = nh11 = (short8v)0;
            nl00 = nl10 = nl01 = nl11 = (short8v)0;
        }

        // ---- compute tile it ----
        {
            short8v ah, al;
            cvt8(a0x, a0y, ah, al);   // ks=0
            acc[0] = __builtin_amdgcn_mfma_f32_32x32x16_bf16(ah, bh00, acc[0], 0, 0, 0);
            acc[0] = __builtin_amdgcn_mfma_f32_32x32x16_bf16(ah, bl00, acc[0], 0, 0, 0);
            acc[0] = __builtin_amdgcn_mfma_f32_32x32x16_bf16(al, bh00, acc[0], 0, 0, 0);
            acc[1] = __builtin_amdgcn_mfma_f32_32x32x16_bf16(ah, bh10, acc[1], 0, 0, 0);
            acc[1] = __builtin_amdgcn_mfma_f32_32x32x16_bf16(ah, bl10, acc[1], 0, 0, 0);
            acc[1] = __builtin_amdgcn_mfma_f32_32x32x16_bf16(al, bh10, acc[1], 0, 0, 0);
            cvt8(a1x, a1y, ah, al);   // ks=1
            acc[0] = __builtin_amdgcn_mfma_f32_32x32x16_bf16(ah, bh01, acc[0], 0, 0, 0);
            acc[0] = __builtin_amdgcn_mfma_f32_32x32x16_bf16(ah, bl01, acc[0], 0, 0, 0);
            acc[0] = __builtin_amdgcn_mfma_f32_32x32x16_bf16(al, bh01, acc[0], 0, 0, 0);
            acc[1] = __builtin_amdgcn_mfma_f32_32x32x16_bf16(ah, bh11, acc[1], 0, 0, 0);
            acc[1] = __builtin_amdgcn_mfma_f32_32x32x16_bf16(ah, bl11, acc[1], 0, 0, 0);
            acc[1] = __builtin_amdgcn_mfma_f32_32x32x16_bf16(al, bh11, acc[1], 0, 0, 0);
        }

        a0x = na0x; a0y = na0y; a1x = na1x; a1y = na1y;
        bh00 = nh00; bh10 = nh10; bh01 = nh01; bh11 = nh11;
        bl00 = nl00; bl10 = nl10; bl01 = nl01; bl11 = nl11;
    }

    // epilogue: C/D layout (m74/m101): col=lane&31, row=(r&3)+8*(r>>2)+4*(lane>>5)
#pragma unroll
    for (int cf = 0; cf < 2; ++cf)
#pragma unroll
        for (int r = 0; r < 16; ++r) {
            int row = rbase + (r & 3) + 8 * (r >> 2) + 4 * hs;
            int col = cbase + cf * 32 + mr;
            C[(size_t)row * F_OUT + col] = acc[cf][r];
        }
}

// ---------------------------------------------------------------------------
// attention coefficients v2: WAVE per node (4 nodes/block).
// lane l holds channels 4l..4l+3 (all in head l>>4); 16-lane-group reduce.
// ---------------------------------------------------------------------------
__global__ __launch_bounds__(256) void attn_coef_kernel(const float* __restrict__ h,
                                                        const float* __restrict__ att_s,
                                                        const float* __restrict__ att_d,
                                                        float* __restrict__ a_s,
                                                        float* __restrict__ a_d)
{
    const int wv = threadIdx.x >> 6;
    const int n  = blockIdx.x * 4 + wv;
    const int l  = threadIdx.x & 63;
    float4 hv = ((const float4*)h)[(size_t)n * 64 + l];
    float4 as = ((const float4*)att_s)[l];
    float4 ad = ((const float4*)att_d)[l];
    float vs = hv.x * as.x + hv.y * as.y + hv.z * as.z + hv.w * as.w;
    float vd = hv.x * ad.x + hv.y * ad.y + hv.z * ad.z + hv.w * ad.w;
#pragma unroll
    for (int o = 1; o < 16; o <<= 1) {
        vs += __shfl_xor(vs, o);
        vd += __shfl_xor(vd, o);
    }
    if ((l & 15) == 0) {
        a_s[n * NH + (l >> 4)] = vs;
        a_d[n * NH + (l >> 4)] = vd;
    }
}

// ---------------------------------------------------------------------------
// CSR build (by destination)
// ---------------------------------------------------------------------------
__global__ void hist_kernel(const int* __restrict__ ei, int* __restrict__ deg)
{
    int e = blockIdx.x * blockDim.x + threadIdx.x;
    if (e < N_EDGES) atomicAdd(&deg[ei[N_EDGES + e]], 1);
}

__global__ __launch_bounds__(1024) void scan_kernel(const int* __restrict__ deg,
                                                    int* __restrict__ rowptr)
{
    __shared__ int sums[1024];
    const int t = threadIdx.x;
    const int chunk = (N_NODES + 1023) / 1024;
    int beg = t * chunk;
    int end = beg + chunk; if (end > N_NODES) end = N_NODES;
    if (beg > N_NODES) beg = N_NODES;
    int s = 0;
    for (int i = beg; i < end; ++i) s += deg[i];
    sums[t] = s;
    __syncthreads();
    for (int o = 1; o < 1024; o <<= 1) {
        int v = (t >= o) ? sums[t - o] : 0;
        __syncthreads();
        sums[t] += v;
        __syncthreads();
    }
    int run = (t == 0) ? 0 : sums[t - 1];
    for (int i = beg; i < end; ++i) { rowptr[i] = run; run += deg[i]; }
    if (t == 1023) rowptr[N_NODES] = run;
}

__global__ void scatter_kernel(const int* __restrict__ ei, int* __restrict__ cursor,
                               int* __restrict__ ssrc, int* __restrict__ edst)
{
    int e = blockIdx.x * blockDim.x + threadIdx.x;
    if (e < N_EDGES) {
        int d = ei[N_EDGES + e];
        int pos = atomicAdd(&cursor[d], 1);
        ssrc[pos] = ei[e];
        edst[pos] = d;
    }
}

// ---------------------------------------------------------------------------
// per-edge logits in CSR order
// ---------------------------------------------------------------------------
__global__ void edge_logit_kernel(const int* __restrict__ ssrc,
                                  const int* __restrict__ edst,
                                  const float* __restrict__ a_s,
                                  const float* __restrict__ a_d,
                                  float* __restrict__ e_csr)
{
    int p = blockIdx.x * 256 + threadIdx.x;
    if (p >= N_EDGES) return;
    int s = ssrc[p], d = edst[p];
    float4 as = ((const float4*)a_s)[s];
    float4 ad = ((const float4*)a_d)[d];
    float4 e;
    e.x = lrelu(as.x + ad.x);
    e.y = lrelu(as.y + ad.y);
    e.z = lrelu(as.z + ad.z);
    e.w = lrelu(as.w + ad.w);
    ((float4*)e_csr)[p] = e;
}

// ---------------------------------------------------------------------------
// GAT aggregation v3: wave per node (r7-verified, unchanged)
// ---------------------------------------------------------------------------
__global__ __launch_bounds__(256) void agg_kernel(const float* __restrict__ h,
                                                  const float* __restrict__ e_csr,
                                                  const float* __restrict__ a_s,
                                                  const float* __restrict__ a_d,
                                                  const int* __restrict__ rowptr,
                                                  const int* __restrict__ ssrc,
                                                  const float* __restrict__ bias,
                                                  float* __restrict__ out)
{
    const int wv = threadIdx.x >> 6;
    const int n  = blockIdx.x * 4 + wv;
    const int l  = threadIdx.x & 63;

    const int beg = rowptr[n];
    const int deg = rowptr[n + 1] - beg;

    // ---- phase A (head hA = l&3) ----
    const int hA = l & 3;
    const float es = lrelu(a_s[n * NH + hA] + a_d[n * NH + hA]);
    const float* ep = e_csr + (size_t)beg * 4;

    float mx = es;
    for (int base = 0; base < deg; base += 16) {
        int i = base + (l >> 2);
        float e = (i < deg) ? ep[(size_t)i * 4 + hA] : -1e30f;
        mx = fmaxf(mx, e);
    }
#pragma unroll
    for (int o = 4; o < 64; o <<= 1) mx = fmaxf(mx, __shfl_xor(mx, o));

    float sm = ((l >> 2) == 0) ? __expf(es - mx) : 0.f;
    for (int base = 0; base < deg; base += 16) {
        int i = base + (l >> 2);
        sm += (i < deg) ? __expf(ep[(size_t)i * 4 + hA] - mx) : 0.f;
    }
#pragma unroll
    for (int o = 4; o < 64; o <<= 1) sm += __shfl_xor(sm, o);
    const float dinv = 1.f / (sm + 1e-16f);

    // ---- rekey to phase B (head hB = l>>4) ----
    const int hB = l >> 4;
    const float mxB = __shfl(mx, hB);
    const float dvB = __shfl(dinv, hB);
    const float esB = __shfl(es, hB);

    // ---- phase B: gather ----
    const float4* h4 = (const float4*)h;
    float4 acc;
    {
        float sa = __expf(esB - mxB) * dvB;
        float4 hv = h4[(size_t)n * 64 + l];
        acc.x = sa * hv.x; acc.y = sa * hv.y; acc.z = sa * hv.z; acc.w = sa * hv.w;
    }
    int i = 0;
    for (; i + 8 <= deg; i += 8) {
        const int p = beg + i;
        int   s[8]; float e[8]; float4 v[8];
#pragma unroll
        for (int j = 0; j < 8; ++j) s[j] = ssrc[p + j];
#pragma unroll
        for (int j = 0; j < 8; ++j) e[j] = e_csr[(size_t)(p + j) * 4 + hB];
#pragma unroll
        for (int j = 0; j < 8; ++j) v[j] = h4[(size_t)s[j] * 64 + l];
#pragma unroll
        for (int j = 0; j < 8; ++j) {
            float a = __expf(e[j] - mxB) * dvB;
            acc.x += a * v[j].x; acc.y += a * v[j].y;
            acc.z += a * v[j].z; acc.w += a * v[j].w;
        }
    }
    for (; i < deg; ++i) {
        const int p = beg + i;
        int sj = ssrc[p];
        float a = __expf(e_csr[(size_t)p * 4 + hB] - mxB) * dvB;
        float4 hv = h4[(size_t)sj * 64 + l];
        acc.x += a * hv.x; acc.y += a * hv.y; acc.z += a * hv.z; acc.w += a * hv.w;
    }
    float4 bv = ((const float4*)bias)[l];
    float4 ov;
    ov.x = fmaxf(acc.x + bv.x, 0.f);
    ov.y = fmaxf(acc.y + bv.y, 0.f);
    ov.z = fmaxf(acc.z + bv.z, 0.f);
    ov.w = fmaxf(acc.w + bv.w, 0.f);
    ((float4*)out)[(size_t)n * 64 + l] = ov;
}

// ---------------------------------------------------------------------------
// graph histogram + pool v2: 4 row-chunk blocks per graph, atomicAdd into
// pre-zeroed out[g].
// ---------------------------------------------------------------------------
__global__ void ghist_kernel(const int* __restrict__ batch, int* __restrict__ gcnt)
{
    int n = blockIdx.x * blockDim.x + threadIdx.x;
    if (n < N_NODES) atomicAdd(&gcnt[batch[n]], 1);
}

__global__ __launch_bounds__(256) void pool_kernel(const float* __restrict__ x,
                                                   const int* __restrict__ gcnt,
                                                   const float* __restrict__ lin_w,
                                                   const float* __restrict__ lin_b,
                                                   float* __restrict__ out)
{
    const int g = blockIdx.x >> 2;
    const int q = blockIdx.x & 3;
    const int t = threadIdx.x;
    __shared__ int s_start;
    if (t == 0) {
        int s = 0;
        for (int i = 0; i < g; ++i) s += gcnt[i];
        s_start = s;
    }
    __syncthreads();
    const int start = s_start;
    const int cnt = gcnt[g];
    const int chunk = (cnt + 3) >> 2;
    int i0 = q * chunk;
    int i1 = i0 + chunk; if (i1 > cnt) i1 = cnt;
    if (i0 > cnt) i0 = cnt;
    float acc = 0.f;
    for (int i = i0; i < i1; ++i) acc += x[(size_t)(start + i) * F_OUT + t];
    float v = acc / fmaxf((float)cnt, 1.f) * lin_w[t];
    __shared__ float red[256];
    red[t] = v;
    __syncthreads();
    for (int o = 128; o > 0; o >>= 1) {
        if (t < o) red[t] += red[t + o];
        __syncthreads();
    }
    if (t == 0) atomicAdd(&out[g], red[0] + (q == 0 ? lin_b[0] : 0.f));
}

// ---------------------------------------------------------------------------
extern "C" void kernel_launch(void* const* d_in, const int* in_sizes, int n_in,
                              void* d_out, int out_size, void* d_ws, size_t ws_size,
                              hipStream_t stream)
{
    const float* x      = (const float*)d_in[0];
    const int*   ei     = (const int*)  d_in[1];
    const int*   batch  = (const int*)  d_in[2];
    const float* W1     = (const float*)d_in[3];
    const float* att_s1 = (const float*)d_in[4];
    const float* att_d1 = (const float*)d_in[5];
    const float* b1     = (const float*)d_in[6];
    const float* W2     = (const float*)d_in[7];
    const float* att_s2 = (const float*)d_in[8];
    const float* att_d2 = (const float*)d_in[9];
    const float* b2     = (const float*)d_in[10];
    const float* lin_w  = (const float*)d_in[11];
    const float* lin_b  = (const float*)d_in[12];
    float* out = (float*)d_out;

    const int Kp1 = 1312;   // 1300 padded to x32
    const int Kp2 = 256;

    size_t off = 0;
    auto carve = [&](size_t bytes) -> void* {
        void* p = (char*)d_ws + off;
        off += (bytes + 255) & ~(size_t)255;
        return p;
    };
    float* hA     = (float*)carve((size_t)N_NODES * F_OUT * 4);
    float* hB     = (float*)carve((size_t)N_NODES * F_OUT * 4);
    float* a_s    = (float*)carve((size_t)N_NODES * NH * 4);
    float* a_d    = (float*)carve((size_t)N_NODES * NH * 4);
    int*   deg    = (int*)  carve((size_t)(N_NODES + 1) * 4);
    int*   rowptr = (int*)  carve((size_t)(N_NODES + 1) * 4);
    int*   cursor = (int*)  carve((size_t)N_NODES * 4);
    int*   ssrc   = (int*)  carve((size_t)N_EDGES * 4);
    int*   edst   = (int*)  carve((size_t)N_EDGES * 4);
    float* e_csr  = (float*)carve((size_t)N_EDGES * NH * 4);
    int*   gcnt   = (int*)  carve((size_t)NG * 4);
    short* Bt1h   = (short*)carve((size_t)F_OUT * Kp1 * 2);
    short* Bt1l   = (short*)carve((size_t)F_OUT * Kp1 * 2);
    short* Bt2h   = (short*)carve((size_t)F_OUT * Kp2 * 2);
    short* Bt2l   = (short*)carve((size_t)F_OUT * Kp2 * 2);
    (void)ws_size; (void)n_in; (void)in_sizes; (void)out_size;

    // ---- CSR build + weight pre-split/pack ----
    hipMemsetAsync(deg, 0, (size_t)(N_NODES + 1) * 4, stream);
    hipMemsetAsync(gcnt, 0, (size_t)NG * 4, stream);
    hipMemsetAsync(out, 0, (size_t)NG * 4, stream);
    hist_kernel<<<(N_EDGES + 255) / 256, 256, 0, stream>>>(ei, deg);
    scan_kernel<<<1, 1024, 0, stream>>>(deg, rowptr);
    hipMemcpyAsync(cursor, rowptr, (size_t)N_NODES * 4, hipMemcpyDeviceToDevice, stream);
    scatter_kernel<<<(N_EDGES + 255) / 256, 256, 0, stream>>>(ei, cursor, ssrc, edst);
    ghist_kernel<<<(N_NODES + 255) / 256, 256, 0, stream>>>(batch, gcnt);
    wsplit_kernel<<<(F_OUT * Kp1 + 255) / 256, 256, 0, stream>>>(W1, Bt1h, Bt1l, F_IN, Kp1);
    wsplit_kernel<<<(F_OUT * Kp2 + 255) / 256, 256, 0, stream>>>(W2, Bt2h, Bt2l, F_OUT, Kp2);

    const int gblocks = N_NODES / BMR;  // 1250
    const int ablocks = N_NODES / 4;    // 10000 (wave per node)
    const int eblocks = (N_EDGES + 255) / 256;

    // ---- layer 1 ----
    gemm_mfma_kernel<<<gblocks, 256, 0, stream>>>(x, Bt1h, Bt1l, hA, F_IN, Kp1);
    attn_coef_kernel<<<ablocks, 256, 0, stream>>>(hA, att_s1, att_d1, a_s, a_d);
    edge_logit_kernel<<<eblocks, 256, 0, stream>>>(ssrc, edst, a_s, a_d, e_csr);
    agg_kernel<<<ablocks, 256, 0, stream>>>(hA, e_csr, a_s, a_d, rowptr, ssrc, b1, hB);

    // ---- layer 2 ----
    gemm_mfma_kernel<<<gblocks, 256, 0, stream>>>(hB, Bt2h, Bt2l, hA, F_OUT, Kp2);
    attn_coef_kernel<<<ablocks, 256, 0, stream>>>(hA, att_s2, att_d2, a_s, a_d);
    edge_logit_kernel<<<eblocks, 256, 0, stream>>>(ssrc, edst, a_s, a_d, e_csr);
    agg_kernel<<<ablocks, 256, 0, stream>>>(hA, e_csr, a_s, a_d, rowptr, ssrc, b2, hB);

    // ---- pool + head ----
    pool_kernel<<<NG * 4, 256, 0, stream>>>(hB, gcnt, lin_w, lin_b, out);
}